// Round 1
// baseline (890.835 us; speedup 1.0000x reference)
//
#include <hip/hip_runtime.h>
#include <math.h>

#define NN 100000
#define NE 3200000
#define FIN 512
#define NH 8
#define C1 8
#define HC1 64
#define C2 10
#define HC2 80

// radix CSR build
#define EPB 4096
#define NBLK 782           // ceil(NE/EPB)
#define NBUK 196           // ceil(NN/512)
#define SCN (NBUK * NBLK)  // 153272
#define SCNB 150           // ceil(SCN/1024)

typedef unsigned int uint;
typedef unsigned short ushort;
using bf16x8 = __attribute__((ext_vector_type(8))) short;
using f32x4  = __attribute__((ext_vector_type(4))) float;

// ---------------- static scratch ----------------
__device__ float g_h1[NN * HC1];        // x @ W1 (fp32, MFMA out)
__device__ float g_hact[NN * HC1];      // elu(agg1 + b1)
__device__ float g_h2[NN * HC2];        // hact @ W2 (fp32)
__device__ uint  g_h1b[NN * 32];        // h1 as bf16 pairs (ch 2p, 2p+1)
__device__ uint  g_h2b[NN * 40];        // h2 as bf16 pairs
__device__ uint  g_w1bt[64 * 256];      // W1 transposed bf16 pairs: [n][kp]
__device__ float g_ssrc[NN * NH];
__device__ float g_sdst[NN * NH];
__device__ int   g_off8[NBUK * 4096];   // per-(node, src-range) CSR starts
__device__ uint  g_pscan[SCN];          // per-(bucket,block) counts -> scanned
__device__ uint  g_bsum2[256];
__device__ uint  g_ebuf[NE];            // packed (dlow<<17)|src, bucket-partitioned
__device__ int   g_csr[NE];

__device__ __forceinline__ float lrelu(float x) { return fmaxf(x, 0.2f * x); }

__device__ __forceinline__ uint bf16_rne(float x) {
  uint u = __float_as_uint(x);
  u += 0x7fffu + ((u >> 16) & 1u);
  return u >> 16;
}
__device__ __forceinline__ uint packbf2(float lo, float hi) {
  return bf16_rne(lo) | (bf16_rne(hi) << 16);
}
__device__ __forceinline__ float blo(uint v) { return __uint_as_float(v << 16); }
__device__ __forceinline__ float bhi(uint v) { return __uint_as_float(v & 0xffff0000u); }

// ---------------- CSR build: radix partition by dst, no global atomics ----------
__global__ __launch_bounds__(256) void p1count_kernel(const int* __restrict__ ei) {
  __shared__ uint cnt[NBUK];
  int tid = threadIdx.x;
  for (int i = tid; i < NBUK; i += 256) cnt[i] = 0;
  __syncthreads();
  const int* dstp = ei + NE;
  int base = blockIdx.x * EPB;
#pragma unroll 4
  for (int k = 0; k < 16; k++) {
    int e = base + k * 256 + tid;
    if (e < NE) atomicAdd(&cnt[dstp[e] >> 9], 1u);
  }
  __syncthreads();
  for (int i = tid; i < NBUK; i += 256) g_pscan[i * NBLK + blockIdx.x] = cnt[i];
}

__global__ __launch_bounds__(1024) void scn_block_kernel() {
  __shared__ uint sd[1024];
  int tid = threadIdx.x;
  int i = blockIdx.x * 1024 + tid;
  uint v = (i < SCN) ? g_pscan[i] : 0;
  sd[tid] = v;
  __syncthreads();
  for (int off = 1; off < 1024; off <<= 1) {
    uint x = (tid >= off) ? sd[tid - off] : 0;
    __syncthreads();
    sd[tid] += x;
    __syncthreads();
  }
  if (i < SCN) g_pscan[i] = sd[tid] - v;  // exclusive within block
  if (tid == 1023) g_bsum2[blockIdx.x] = sd[1023];
}

__global__ void scn_tops_kernel() {  // 1 block, 256 threads
  __shared__ uint sd[256];
  int tid = threadIdx.x;
  uint v = (tid < SCNB) ? g_bsum2[tid] : 0;
  sd[tid] = v;
  __syncthreads();
  for (int off = 1; off < 256; off <<= 1) {
    uint x = (tid >= off) ? sd[tid - off] : 0;
    __syncthreads();
    sd[tid] += x;
    __syncthreads();
  }
  g_bsum2[tid] = sd[tid] - v;  // exclusive scan of block sums
}

__global__ __launch_bounds__(1024) void scn_add_kernel() {
  int i = blockIdx.x * 1024 + threadIdx.x;
  if (i < SCN) g_pscan[i] += g_bsum2[i >> 10];
}

__global__ __launch_bounds__(256) void p1scatter_kernel(const int* __restrict__ ei) {
  __shared__ uint cur[NBUK];
  int tid = threadIdx.x;
  for (int i = tid; i < NBUK; i += 256) cur[i] = g_pscan[i * NBLK + blockIdx.x];
  __syncthreads();
  const int* srcp = ei;
  const int* dstp = ei + NE;
  int base = blockIdx.x * EPB;
#pragma unroll 4
  for (int k = 0; k < 16; k++) {
    int e = base + k * 256 + tid;
    if (e < NE) {
      int d = dstp[e], s = srcp[e];
      uint pos = atomicAdd(&cur[d >> 9], 1u);  // LDS atomic
      g_ebuf[pos] = ((uint)(d & 511) << 17) | (uint)s;
    }
  }
}

// Pass 2: per-bucket 4096-bin (dlow x src-range) histogram/scan/scatter.
// Emits per-(node, src-range) offsets g_off8 so the agg kernels can sweep
// src ranges as an outer loop (phase-synchronized across waves) => each
// XCD's concurrent gather working set is one 2.6MB range, not the 16MB table.
__global__ __launch_bounds__(1024) void p2build_kernel() {
  __shared__ uint hist[4096];   // reused as cursors in pass 2
  __shared__ uint excl[4096];
  __shared__ uint tsum[1024];
  int tid = threadIdx.x;
  int b = blockIdx.x;
  uint bstart = g_pscan[b * NBLK];
  uint bend = (b < NBUK - 1) ? g_pscan[(b + 1) * NBLK] : NE;
  for (int i = tid; i < 4096; i += 1024) hist[i] = 0;
  __syncthreads();
  for (uint j = bstart + tid; j < bend; j += 1024) {
    uint v = g_ebuf[j];
    uint bin = ((v >> 17) << 3) | ((v & 0x1FFFFu) >> 14);
    atomicAdd(&hist[bin], 1u);
  }
  __syncthreads();
  uint h0 = hist[tid * 4 + 0], h1 = hist[tid * 4 + 1];
  uint h2 = hist[tid * 4 + 2], h3 = hist[tid * 4 + 3];
  uint s1 = h0 + h1, s2 = s1 + h2, s3 = s2 + h3;
  tsum[tid] = s3;
  __syncthreads();
  for (int off = 1; off < 1024; off <<= 1) {
    uint x = (tid >= off) ? tsum[tid - off] : 0;
    __syncthreads();
    tsum[tid] += x;
    __syncthreads();
  }
  uint te = tsum[tid] - s3;  // exclusive over threads
  excl[tid * 4 + 0] = te;
  excl[tid * 4 + 1] = te + h0;
  excl[tid * 4 + 2] = te + s1;
  excl[tid * 4 + 3] = te + s2;
  __syncthreads();
  for (int i = tid; i < 4096; i += 1024)
    g_off8[b * 4096 + i] = (int)(bstart + excl[i]);   // start of (node, range)
  for (int i = tid; i < 4096; i += 1024) hist[i] = excl[i];  // cursors
  __syncthreads();
  for (uint j = bstart + tid; j < bend; j += 1024) {
    uint v = g_ebuf[j];
    uint bin = ((v >> 17) << 3) | ((v & 0x1FFFFu) >> 14);
    uint pos = bstart + atomicAdd(&hist[bin], 1u);  // LDS atomic
    g_csr[pos] = (int)(v & 0x1FFFFu);
  }
}

// ---------------- W1 -> bf16 transposed pairs ----------------
__global__ __launch_bounds__(256) void w1cast_kernel(const float* __restrict__ W) {
  int idx = blockIdx.x * 256 + threadIdx.x;  // 0..16383
  int n = idx & 63, kp = idx >> 6;           // kp 0..255
  float lo = W[(2 * kp) * HC1 + n];
  float hi = W[(2 * kp + 1) * HC1 + n];
  g_w1bt[n * 256 + kp] = packbf2(lo, hi);
}

// ---------------- GEMM1: g_h1 = X[NN,512] @ W1[512,64] via bf16 MFMA ------------
__device__ __forceinline__ int sw_idx(int row, int g) {
  return row * 32 + ((g ^ (row & 7)) << 2);
}

__global__ __launch_bounds__(256) void gemm1_kernel(const float* __restrict__ X) {
  __shared__ uint sA[64 * 32];
  __shared__ uint sB[64 * 32];
  int t = threadIdx.x;
  int w = t >> 6, l = t & 63;
  int q = l >> 4, c = l & 15;
  int r0 = blockIdx.x * 64;
  int sr = t >> 2;             // 0..63 (row / n)
  int sc = t & 3;              // quarter
  int xrow = r0 + sr; if (xrow >= NN) xrow = NN - 1;
  const float* xbase = &X[(long)xrow * FIN + sc * 16];
  const uint* wbase = &g_w1bt[sr * 256 + sc * 8];
  f32x4 acc[4] = {{0.f,0.f,0.f,0.f},{0.f,0.f,0.f,0.f},{0.f,0.f,0.f,0.f},{0.f,0.f,0.f,0.f}};
  for (int k0 = 0; k0 < FIN; k0 += 64) {
    __syncthreads();
    float4 f0 = *(const float4*)&xbase[k0 + 0];
    float4 f1 = *(const float4*)&xbase[k0 + 4];
    float4 f2 = *(const float4*)&xbase[k0 + 8];
    float4 f3 = *(const float4*)&xbase[k0 + 12];
    uint4 a0 = make_uint4(packbf2(f0.x, f0.y), packbf2(f0.z, f0.w),
                          packbf2(f1.x, f1.y), packbf2(f1.z, f1.w));
    uint4 a1 = make_uint4(packbf2(f2.x, f2.y), packbf2(f2.z, f2.w),
                          packbf2(f3.x, f3.y), packbf2(f3.z, f3.w));
    *(uint4*)&sA[sw_idx(sr, sc * 2 + 0)] = a0;
    *(uint4*)&sA[sw_idx(sr, sc * 2 + 1)] = a1;
    uint4 b0 = *(const uint4*)&wbase[(k0 >> 1) + 0];
    uint4 b1 = *(const uint4*)&wbase[(k0 >> 1) + 4];
    *(uint4*)&sB[sw_idx(sr, sc * 2 + 0)] = b0;
    *(uint4*)&sB[sw_idx(sr, sc * 2 + 1)] = b1;
    __syncthreads();
#pragma unroll
    for (int ks = 0; ks < 2; ks++) {
      int g = ks * 4 + q;
      bf16x8 a = *(const bf16x8*)&sA[sw_idx(w * 16 + c, g)];
#pragma unroll
      for (int nt = 0; nt < 4; nt++) {
        bf16x8 b = *(const bf16x8*)&sB[sw_idx(nt * 16 + c, g)];
        acc[nt] = __builtin_amdgcn_mfma_f32_16x16x32_bf16(a, b, acc[nt], 0, 0, 0);
      }
    }
  }
  int orow0 = r0 + w * 16 + q * 4;
#pragma unroll
  for (int nt = 0; nt < 4; nt++) {
#pragma unroll
    for (int r = 0; r < 4; r++) {
      int row = orow0 + r;
      if (row < NN) g_h1[row * HC1 + nt * 16 + c] = acc[nt][r];
    }
  }
}

// ---------------- attention scores + bf16 packing ----------------
template <int LAYER>
__global__ __launch_bounds__(256) void s_kernel(const float* __restrict__ a_src,
                                                const float* __restrict__ a_dst) {
  constexpr int C = (LAYER == 1) ? C1 : C2;
  const float* Hm = (LAYER == 1) ? g_h1 : g_h2;
  uint* Hb = (LAYER == 1) ? g_h1b : g_h2b;
  int t = blockIdx.x * 256 + threadIdx.x;
  if (t >= NN * NH) return;
  int h = t & 7;
  const float* row = &Hm[t * C];
  float ss = 0.f, sdd = 0.f;
  float vals[C];
#pragma unroll
  for (int c = 0; c < C; c++) {
    float v = row[c];
    vals[c] = v;
    ss = fmaf(v, a_src[h * C + c], ss);
    sdd = fmaf(v, a_dst[h * C + c], sdd);
  }
  g_ssrc[t] = ss;
  g_sdst[t] = sdd;
#pragma unroll
  for (int j = 0; j < C / 2; j++)
    Hb[t * (C / 2) + j] = packbf2(vals[2 * j], vals[2 * j + 1]);
}

// ---- layer-1 aggregation: 8 nodes/wave, src-range outer loop (phase-sync) ----
// All waves sweep src ranges in (rotated) lockstep => per-XCD concurrent gather
// working set = one 16K-node range (2.1MB h1b) which fits the 4MB XCD L2.
__global__ __launch_bounds__(256) void agg1_kernel(const float* __restrict__ b1) {
  int wv = __builtin_amdgcn_readfirstlane((int)((blockIdx.x * 256 + threadIdx.x) >> 6));
  int n0 = wv * 8;
  int lane = threadIdx.x & 63;
  int h = lane >> 3;
  int xcd = blockIdx.x & 7;
  const ushort* __restrict__ h1u = (const ushort*)g_h1b;  // bf16 channel view
  float acc[8], wsum[8], sdv[8];
#pragma unroll
  for (int s = 0; s < 8; s++) {
    acc[s] = 0.f;
    wsum[s] = 0.f;
    sdv[s] = g_sdst[(n0 + s) * NH + h];
  }
  for (int rr = 0; rr < 8; rr++) {
    int ra = (rr + xcd) & 7;
#pragma unroll
    for (int s = 0; s < 8; s++) {
      int n = n0 + s;
      int j  = __builtin_amdgcn_readfirstlane(g_off8[n * 8 + ra]);
      int j1 = __builtin_amdgcn_readfirstlane(g_off8[n * 8 + ra + 1]);
      if (j == j1) continue;
      float sd = sdv[s];
      for (; j + 4 <= j1; j += 4) {
        int s0 = __builtin_amdgcn_readfirstlane(g_csr[j + 0]);
        int s1 = __builtin_amdgcn_readfirstlane(g_csr[j + 1]);
        int s2 = __builtin_amdgcn_readfirstlane(g_csr[j + 2]);
        int s3 = __builtin_amdgcn_readfirstlane(g_csr[j + 3]);
        float t0 = g_ssrc[s0 * NH + h];
        float t1 = g_ssrc[s1 * NH + h];
        float t2 = g_ssrc[s2 * NH + h];
        float t3 = g_ssrc[s3 * NH + h];
        uint v0 = h1u[s0 * HC1 + lane];
        uint v1 = h1u[s1 * HC1 + lane];
        uint v2 = h1u[s2 * HC1 + lane];
        uint v3 = h1u[s3 * HC1 + lane];
        float e0 = __expf(lrelu(t0 + sd));
        float e1 = __expf(lrelu(t1 + sd));
        float e2 = __expf(lrelu(t2 + sd));
        float e3 = __expf(lrelu(t3 + sd));
        acc[s] = fmaf(__uint_as_float(v0 << 16), e0, acc[s]);
        acc[s] = fmaf(__uint_as_float(v1 << 16), e1, acc[s]);
        acc[s] = fmaf(__uint_as_float(v2 << 16), e2, acc[s]);
        acc[s] = fmaf(__uint_as_float(v3 << 16), e3, acc[s]);
        wsum[s] += (e0 + e1) + (e2 + e3);
      }
      for (; j < j1; j++) {
        int sx = __builtin_amdgcn_readfirstlane(g_csr[j]);
        float e = __expf(lrelu(g_ssrc[sx * NH + h] + sd));
        acc[s] = fmaf(__uint_as_float((uint)h1u[sx * HC1 + lane] << 16), e, acc[s]);
        wsum[s] += e;
      }
    }
    __syncthreads();  // keep the block's 4 waves phase-aligned
  }
#pragma unroll
  for (int s = 0; s < 8; s++) {
    int n = n0 + s;
    float es = __expf(lrelu(g_ssrc[n * NH + h] + sdv[s]));
    float a = fmaf(g_h1[n * HC1 + lane], es, acc[s]);   // self loop fp32
    float ws = wsum[s] + es;
    float v = a * (1.f / ws) + b1[lane];
    g_hact[n * HC1 + lane] = v > 0.f ? v : __expf(v) - 1.f;  // ELU
  }
}

// ---------------- GEMM2: g_h2 = g_hact[NN,64] @ W2[64,80] ----------------
__global__ __launch_bounds__(256) void gemm2_kernel(const float* __restrict__ W) {
  __shared__ float sW[64 * HC2 + 64];
  int tid = threadIdx.x;
  for (int i = tid; i < 64 * HC2; i += 256) sW[i] = W[i];
  for (int i = 64 * HC2 + tid; i < 64 * HC2 + 64; i += 256) sW[i] = 0.f;
  __syncthreads();
  int lane = tid & 63;
  int w0 = (blockIdx.x * 256 + tid) >> 6;
  for (int r = w0; r < NN; r += 8192) {
    float v = g_hact[r * HC1 + lane];
    float acc0 = 0.f, acc1 = 0.f;
#pragma unroll
    for (int k = 0; k < 64; k++) {
      float xk = __shfl(v, k);
      acc0 = fmaf(xk, sW[k * HC2 + lane], acc0);
      acc1 = fmaf(xk, sW[k * HC2 + 64 + lane], acc1);
    }
    g_h2[r * HC2 + lane] = acc0;
    if (lane < 16) g_h2[r * HC2 + 64 + lane] = acc1;
  }
}

// ---- layer-2 aggregation: 8 nodes/wave range-sync + bias + log_softmax ------
__global__ __launch_bounds__(256) void agg2_kernel(float* __restrict__ out,
                                                   const float* __restrict__ b2) {
  int wv = __builtin_amdgcn_readfirstlane((int)((blockIdx.x * 256 + threadIdx.x) >> 6));
  int n0 = wv * 8;
  int lane = threadIdx.x & 63;
  int p = lane < 40 ? lane : 39;
  int h = p / 5;
  int xcd = blockIdx.x & 7;
  float acc0[8], acc1[8], wsum[8], sdv[8];
#pragma unroll
  for (int s = 0; s < 8; s++) {
    acc0[s] = 0.f;
    acc1[s] = 0.f;
    wsum[s] = 0.f;
    sdv[s] = g_sdst[(n0 + s) * NH + h];
  }
  for (int rr = 0; rr < 8; rr++) {
    int ra = (rr + xcd) & 7;
#pragma unroll
    for (int s = 0; s < 8; s++) {
      int n = n0 + s;
      int j  = __builtin_amdgcn_readfirstlane(g_off8[n * 8 + ra]);
      int j1 = __builtin_amdgcn_readfirstlane(g_off8[n * 8 + ra + 1]);
      if (j == j1) continue;
      float sd = sdv[s];
      for (; j + 4 <= j1; j += 4) {
        int s0 = __builtin_amdgcn_readfirstlane(g_csr[j + 0]);
        int s1 = __builtin_amdgcn_readfirstlane(g_csr[j + 1]);
        int s2 = __builtin_amdgcn_readfirstlane(g_csr[j + 2]);
        int s3 = __builtin_amdgcn_readfirstlane(g_csr[j + 3]);
        float t0 = g_ssrc[s0 * NH + h];
        float t1 = g_ssrc[s1 * NH + h];
        float t2 = g_ssrc[s2 * NH + h];
        float t3 = g_ssrc[s3 * NH + h];
        uint v0 = g_h2b[s0 * 40 + p];
        uint v1 = g_h2b[s1 * 40 + p];
        uint v2 = g_h2b[s2 * 40 + p];
        uint v3 = g_h2b[s3 * 40 + p];
        float e0 = __expf(lrelu(t0 + sd));
        float e1 = __expf(lrelu(t1 + sd));
        float e2 = __expf(lrelu(t2 + sd));
        float e3 = __expf(lrelu(t3 + sd));
        acc0[s] = fmaf(blo(v0), e0, acc0[s]); acc1[s] = fmaf(bhi(v0), e0, acc1[s]);
        acc0[s] = fmaf(blo(v1), e1, acc0[s]); acc1[s] = fmaf(bhi(v1), e1, acc1[s]);
        acc0[s] = fmaf(blo(v2), e2, acc0[s]); acc1[s] = fmaf(bhi(v2), e2, acc1[s]);
        acc0[s] = fmaf(blo(v3), e3, acc0[s]); acc1[s] = fmaf(bhi(v3), e3, acc1[s]);
        wsum[s] += (e0 + e1) + (e2 + e3);
      }
      for (; j < j1; j++) {
        int sx = __builtin_amdgcn_readfirstlane(g_csr[j]);
        float e = __expf(lrelu(g_ssrc[sx * NH + h] + sd));
        uint v = g_h2b[sx * 40 + p];
        acc0[s] = fmaf(blo(v), e, acc0[s]); acc1[s] = fmaf(bhi(v), e, acc1[s]);
        wsum[s] += e;
      }
    }
    __syncthreads();  // keep the block's 4 waves phase-aligned
  }
#pragma unroll
  for (int s = 0; s < 8; s++) {
    int n = n0 + s;
    float es = __expf(lrelu(g_ssrc[n * NH + h] + sdv[s]));
    float a0 = fmaf(g_h2[n * HC2 + 2 * p], es, acc0[s]);
    float a1 = fmaf(g_h2[n * HC2 + 2 * p + 1], es, acc1[s]);
    float ws = wsum[s] + es;
    float inv = 1.f / ws;
    float v0 = a0 * inv + b2[2 * p];
    float v1 = a1 * inv + b2[2 * p + 1];
    float mx = fmaxf(v0, v1);
    for (int o = 32; o; o >>= 1) mx = fmaxf(mx, __shfl_xor(mx, o));
    float spart = (lane < 40) ? __expf(v0 - mx) + __expf(v1 - mx) : 0.f;
    for (int o = 32; o; o >>= 1) spart += __shfl_xor(spart, o);
    float lse = mx + __logf(spart);
    if (lane < 40) *(float2*)&out[n * HC2 + 2 * p] = make_float2(v0 - lse, v1 - lse);
  }
}

// ---------------- launch ----------------
extern "C" void kernel_launch(void* const* d_in, const int* in_sizes, int n_in,
                              void* d_out, int out_size, void* d_ws, size_t ws_size,
                              hipStream_t stream) {
  (void)in_sizes; (void)n_in; (void)out_size; (void)d_ws; (void)ws_size;
  const float* x   = (const float*)d_in[0];
  const int*   ei  = (const int*)d_in[1];
  const float* W1  = (const float*)d_in[2];
  const float* as1 = (const float*)d_in[3];
  const float* ad1 = (const float*)d_in[4];
  const float* b1  = (const float*)d_in[5];
  const float* W2  = (const float*)d_in[6];
  const float* as2 = (const float*)d_in[7];
  const float* ad2 = (const float*)d_in[8];
  const float* b2  = (const float*)d_in[9];
  float* out = (float*)d_out;

  // CSR build (radix partition + src-range ordering; shared by both layers)
  p1count_kernel<<<NBLK, 256, 0, stream>>>(ei);
  scn_block_kernel<<<SCNB, 1024, 0, stream>>>();
  scn_tops_kernel<<<1, 256, 0, stream>>>();
  scn_add_kernel<<<SCNB, 1024, 0, stream>>>();
  p1scatter_kernel<<<NBLK, 256, 0, stream>>>(ei);
  p2build_kernel<<<NBUK, 1024, 0, stream>>>();

  // layer 1
  w1cast_kernel<<<64, 256, 0, stream>>>(W1);
  gemm1_kernel<<<1563, 256, 0, stream>>>(x);
  s_kernel<1><<<3125, 256, 0, stream>>>(as1, ad1);
  agg1_kernel<<<3125, 256, 0, stream>>>(b1);

  // layer 2
  gemm2_kernel<<<2048, 256, 0, stream>>>(W2);
  s_kernel<2><<<3125, 256, 0, stream>>>(as2, ad2);
  agg2_kernel<<<3125, 256, 0, stream>>>(out, b2);
}